// Round 2
// baseline (573.472 us; speedup 1.0000x reference)
//
#include <hip/hip_runtime.h>
#include <hip/hip_fp16.h>

#define N_NODES_C 100000
#define N_EDGES_C 1600000
#define N_GRAPHS_C 2000
#define HID 128
#define BN_EPS_C 1e-5f
#define NBUCK 391          // ceil(100000 / 256) buckets of 256 nodes
#define PART_TILE 4096     // edges per block in hist/partition kernels

typedef _Float16 half8 __attribute__((ext_vector_type(8)));
typedef float float4v __attribute__((ext_vector_type(4)));

// ---------------- CSR build: bucket partition ----------------

__global__ __launch_bounds__(256) void kb_hist(const int* __restrict__ dst, int* __restrict__ bcount) {
    __shared__ int hist[NBUCK];
    const int t = threadIdx.x;
    for (int b = t; b < NBUCK; b += 256) hist[b] = 0;
    __syncthreads();
    const int e0 = blockIdx.x * PART_TILE;
    #pragma unroll
    for (int k = 0; k < 16; k++) {
        int e = e0 + k * 256 + t;
        if (e < N_EDGES_C) atomicAdd(&hist[dst[e] >> 8], 1);
    }
    __syncthreads();
    for (int b = t; b < NBUCK; b += 256) {
        int c = hist[b];
        if (c) atomicAdd(&bcount[b], c);
    }
}

__global__ __launch_bounds__(512) void kb_scan(const int* __restrict__ bcount,
                                               int* __restrict__ bbase, int* __restrict__ bcursor) {
    __shared__ int s[512];
    const int t = threadIdx.x;
    int v = (t < NBUCK) ? bcount[t] : 0;
    s[t] = v;
    __syncthreads();
    for (int off = 1; off < 512; off <<= 1) {
        int u = (t >= off) ? s[t - off] : 0;
        __syncthreads();
        s[t] += u;
        __syncthreads();
    }
    if (t < NBUCK) { int e = s[t] - v; bbase[t] = e; bcursor[t] = e; }
    if (t == 0) bbase[NBUCK] = N_EDGES_C;
}

__global__ __launch_bounds__(256) void kb_part(const int* __restrict__ src, const int* __restrict__ dst,
                                               int* __restrict__ bcursor, int2* __restrict__ ebuf) {
    __shared__ int hist[NBUCK];
    __shared__ int startA[NBUCK];
    __shared__ int lcur[NBUCK];
    const int t = threadIdx.x;
    for (int b = t; b < NBUCK; b += 256) { hist[b] = 0; lcur[b] = 0; }
    __syncthreads();
    const int e0 = blockIdx.x * PART_TILE;
    #pragma unroll
    for (int k = 0; k < 16; k++) {
        int e = e0 + k * 256 + t;
        if (e < N_EDGES_C) atomicAdd(&hist[dst[e] >> 8], 1);
    }
    __syncthreads();
    for (int b = t; b < NBUCK; b += 256) {
        int c = hist[b];
        startA[b] = c ? atomicAdd(&bcursor[b], c) : 0;
    }
    __syncthreads();
    #pragma unroll
    for (int k = 0; k < 16; k++) {
        int e = e0 + k * 256 + t;
        if (e < N_EDGES_C) {
            int d = dst[e];
            int b = d >> 8;
            int pos = startA[b] + atomicAdd(&lcur[b], 1);
            ebuf[pos] = make_int2(src[e], d);
        }
    }
}

// One block per bucket: local count+scan of 256 nodes -> offs, norm, csr_src (all writes bucket-local).
__global__ __launch_bounds__(256) void kb_fill(const int2* __restrict__ ebuf, const int* __restrict__ bbase,
                                               int* __restrict__ csr_src, int* __restrict__ offs,
                                               float* __restrict__ norm) {
    __shared__ int s[256];
    __shared__ int excl[256];
    __shared__ int lcur[256];
    const int b = blockIdx.x, t = threadIdx.x;
    const int base = b << 8;
    const int e0 = bbase[b], e1 = bbase[b + 1];
    s[t] = 0; lcur[t] = 0;
    __syncthreads();
    for (int e = e0 + t; e < e1; e += 256)
        atomicAdd(&s[ebuf[e].y & 255], 1);
    __syncthreads();
    int own = s[t];
    for (int off = 1; off < 256; off <<= 1) {
        int v = (t >= off) ? s[t - off] : 0;
        __syncthreads();
        s[t] += v;
        __syncthreads();
    }
    excl[t] = s[t] - own;
    int node = base + t;
    if (node < N_NODES_C) {
        offs[node] = e0 + (s[t] - own);
        norm[node] = rsqrtf((float)own + 1.0f);
    }
    if (b == 0 && t == 0) offs[N_NODES_C] = N_EDGES_C;
    __syncthreads();
    for (int e = e0 + t; e < e1; e += 256) {
        int2 p = ebuf[e];
        int l = p.y & 255;
        int pos = e0 + excl[l] + atomicAdd(&lcur[l], 1);
        csr_src[pos] = p.x;
    }
}

// ---------------- precompute: x -> fp16, W -> fp16 transposed [n][k] ----------------

__global__ __launch_bounds__(256) void k_cast(const float* __restrict__ x, _Float16* __restrict__ xh) {
    long i = ((long)blockIdx.x * 256 + threadIdx.x) * 8;
    float4 a = *(const float4*)&x[i];
    float4 b = *(const float4*)&x[i + 4];
    _Float16 p[8] = {(_Float16)a.x, (_Float16)a.y, (_Float16)a.z, (_Float16)a.w,
                     (_Float16)b.x, (_Float16)b.y, (_Float16)b.z, (_Float16)b.w};
    *(half8*)&xh[i] = *(half8*)p;
}

__global__ __launch_bounds__(256) void k_tw(const float* __restrict__ Ws_all, _Float16* __restrict__ WT) {
    int idx = blockIdx.x * 256 + threadIdx.x;     // 4*128*128 = 65536
    int l = idx >> 14, r = idx & 16383, k = r >> 7, n = r & 127;
    WT[l * 16384 + n * HID + k] = (_Float16)Ws_all[idx];
}

// ---------------- MFMA GEMM: Y[r,:] = norm[r] * (A[r,:] @ W), fp16 in/out ----------------
// Operand swap: mfma(A_op=W^T frag, B_op=node rows) -> D[channel][node]; lane holds 4
// consecutive channels for one node -> packed 8B stores. 4 waves split 128 channels.

__global__ __launch_bounds__(256) void k_gemm(const _Float16* __restrict__ Ah,
                                              const _Float16* __restrict__ WT,   // [128 n][128 k] fp16
                                              const float* __restrict__ norm,
                                              _Float16* __restrict__ Y, int nrows) {
    __shared__ _Float16 Wt[HID][136];   // [n][k], pitch 136 halves (272B: 2-way bank alias = free)
    const int tid = threadIdx.x;
    #pragma unroll
    for (int t = 0; t < 8; t++) {
        int off = tid * 8 + t * 2048;
        half8 v = *(const half8*)&WT[off];
        *(half8*)&Wt[off >> 7][off & 127] = v;
    }
    __syncthreads();

    const int wave = tid >> 6, lane = tid & 63, quad = lane >> 4, l16 = lane & 15;
    half8 Wf[2][4];
    #pragma unroll
    for (int c = 0; c < 2; c++)
        #pragma unroll
        for (int ks = 0; ks < 4; ks++)
            Wf[c][ks] = *(const half8*)&Wt[(wave * 2 + c) * 16 + l16][ks * 32 + quad * 8];

    const int nbase = blockIdx.x * 128;
    #pragma unroll
    for (int t = 0; t < 8; t++) {
        int node = nbase + t * 16 + l16;
        bool ok = node < nrows;
        half8 Af[4];
        const _Float16* arow = Ah + (long)node * HID;
        #pragma unroll
        for (int ks = 0; ks < 4; ks++)
            Af[ks] = ok ? *(const half8*)&arow[ks * 32 + quad * 8] : half8{};
        float4v a0 = {0.f, 0.f, 0.f, 0.f}, a1 = {0.f, 0.f, 0.f, 0.f};
        #pragma unroll
        for (int ks = 0; ks < 4; ks++) {
            a0 = __builtin_amdgcn_mfma_f32_16x16x32_f16(Wf[0][ks], Af[ks], a0, 0, 0, 0);
            a1 = __builtin_amdgcn_mfma_f32_16x16x32_f16(Wf[1][ks], Af[ks], a1, 0, 0, 0);
        }
        if (ok) {
            float nv = norm[node];
            _Float16 p0[4], p1[4];
            #pragma unroll
            for (int r = 0; r < 4; r++) {
                p0[r] = (_Float16)(a0[r] * nv);
                p1[r] = (_Float16)(a1[r] * nv);
            }
            *(ushort4*)&Y[(long)node * HID + (wave * 2 + 0) * 16 + quad * 4] = *(ushort4*)p0;
            *(ushort4*)&Y[(long)node * HID + (wave * 2 + 1) * 16 + quad * 4] = *(ushort4*)p1;
        }
    }
}

// ---------------- Aggregation + bias + BN(eval) + ReLU ----------------
// One wave per node: 4 edge-groups of 16 lanes; each group gathers a full 256B row
// with half8 (16B/lane) loads -> 4 edges per load round, 16 edges per iteration in ONE
// idx->gather->add chain. Tail is one predicated chain. Cross-group reduce = 2 shuffles.

__global__ __launch_bounds__(256) void k_agg(const _Float16* __restrict__ y, const int* __restrict__ offs,
                                             const int* __restrict__ csr_src, const float* __restrict__ norm,
                                             const float* __restrict__ bias, const float* __restrict__ mean,
                                             const float* __restrict__ gamma, const float* __restrict__ var,
                                             const float* __restrict__ beta, _Float16* __restrict__ h) {
    const int wave = threadIdx.x >> 6;
    const int lane = threadIdx.x & 63;
    const int g  = lane >> 4;        // edge group 0..3
    const int sl = lane & 15;        // sub-lane within group
    const int c  = sl << 3;          // channel base (8 channels/lane)
    const int i  = blockIdx.x * 4 + wave;

    const int e0 = offs[i], e1 = offs[i + 1];
    const _Float16* __restrict__ yc = y + c;

    float acc[8] = {0.f, 0.f, 0.f, 0.f, 0.f, 0.f, 0.f, 0.f};

    // self-loop term: group 0 only (y already scaled by norm[src] in k_gemm)
    if (g == 0) {
        half8 v = *(const half8*)&yc[(long)i * HID];
        #pragma unroll
        for (int r = 0; r < 8; r++) acc[r] += (float)v[r];
    }

    int e = e0;
    // main: 16 edges per iteration, 4 independent 16B gathers in flight
    while (e + 16 <= e1) {
        int s0 = csr_src[e + g];
        int s1 = csr_src[e + g + 4];
        int s2 = csr_src[e + g + 8];
        int s3 = csr_src[e + g + 12];
        half8 v0 = *(const half8*)&yc[(long)s0 * HID];
        half8 v1 = *(const half8*)&yc[(long)s1 * HID];
        half8 v2 = *(const half8*)&yc[(long)s2 * HID];
        half8 v3 = *(const half8*)&yc[(long)s3 * HID];
        #pragma unroll
        for (int r = 0; r < 8; r++)
            acc[r] += ((float)v0[r] + (float)v1[r]) + ((float)v2[r] + (float)v3[r]);
        e += 16;
    }
    // tail: up to 15 edges, single predicated chain (inactive vectors stay zero)
    if (e < e1) {
        const int q = e1 - 1;
        int r0 = e + g, r1 = r0 + 4, r2 = r0 + 8, r3 = r0 + 12;
        int s0 = csr_src[min(r0, q)];
        int s1 = csr_src[min(r1, q)];
        int s2 = csr_src[min(r2, q)];
        int s3 = csr_src[min(r3, q)];
        half8 v0 = half8{}, v1 = half8{}, v2 = half8{}, v3 = half8{};
        if (r0 < e1) v0 = *(const half8*)&yc[(long)s0 * HID];
        if (r1 < e1) v1 = *(const half8*)&yc[(long)s1 * HID];
        if (r2 < e1) v2 = *(const half8*)&yc[(long)s2 * HID];
        if (r3 < e1) v3 = *(const half8*)&yc[(long)s3 * HID];
        #pragma unroll
        for (int r = 0; r < 8; r++)
            acc[r] += ((float)v0[r] + (float)v1[r]) + ((float)v2[r] + (float)v3[r]);
    }

    // reduce the 4 edge-groups: butterfly over lanes ^16 and ^32
    #pragma unroll
    for (int r = 0; r < 8; r++) {
        acc[r] += __shfl_xor(acc[r], 16);
        acc[r] += __shfl_xor(acc[r], 32);
    }

    // epilogue: group 0's 16 lanes cover all 128 channels (8 each)
    if (g == 0) {
        const float ni = norm[i];
        _Float16 p[8];
        #pragma unroll
        for (int r = 0; r < 8; r++) {
            int j = c + r;
            float v = (acc[r] * ni + bias[j] - mean[j]) * (gamma[j] * rsqrtf(var[j] + BN_EPS_C)) + beta[j];
            p[r] = (_Float16)fmaxf(v, 0.f);
        }
        *(half8*)&h[(long)i * HID + c] = *(half8*)p;   // FIX: + c (was missing -> all lanes hit same addr)
    }
}

// ---------------- Pooling (batch sorted -> run-length local accumulation) ----------------

__global__ __launch_bounds__(128) void k_pool(const __half* __restrict__ h, const int* __restrict__ batch,
                                              float* __restrict__ psum, int* __restrict__ pcount) {
    const int j = threadIdx.x;
    const int i0 = blockIdx.x * 128;
    const int iend = min(i0 + 128, N_NODES_C);
    if (i0 >= N_NODES_C) return;
    float acc = 0.f;
    int cur = batch[i0];
    int runStart = i0;
    for (int i = i0; i < iend; i++) {
        int g = batch[i];
        if (g != cur) {
            atomicAdd(&psum[(long)cur * HID + j], acc);
            if (j == 0) atomicAdd(&pcount[cur], i - runStart);
            acc = 0.f; cur = g; runStart = i;
        }
        acc += __half2float(h[(long)i * HID + j]);
    }
    atomicAdd(&psum[(long)cur * HID + j], acc);
    if (j == 0) atomicAdd(&pcount[cur], iend - runStart);
}

__global__ __launch_bounds__(128) void k_final(const float* __restrict__ psum, const int* __restrict__ pcount,
                                               const float* __restrict__ W_out, const float* __restrict__ b_out,
                                               float* __restrict__ out) {
    __shared__ float red[128][5];
    const int g = blockIdx.x, j = threadIdx.x;
    float cnt = fmaxf((float)pcount[g], 1.f);
    float p = psum[(long)g * HID + j] / cnt;
    #pragma unroll
    for (int o = 0; o < 5; o++) red[j][o] = p * W_out[j * 5 + o];
    __syncthreads();
    for (int off = 64; off >= 1; off >>= 1) {
        if (j < off) {
            #pragma unroll
            for (int o = 0; o < 5; o++) red[j][o] += red[j + off][o];
        }
        __syncthreads();
    }
    if (j < 5) out[g * 5 + j] = red[0][j] + b_out[j];
}

// ---------------- launch ----------------

extern "C" void kernel_launch(void* const* d_in, const int* in_sizes, int n_in,
                              void* d_out, int out_size, void* d_ws, size_t ws_size,
                              hipStream_t stream) {
    const float* x        = (const float*)d_in[0];
    const int*   eidx     = (const int*)d_in[1];
    const int*   src      = eidx;
    const int*   dst      = eidx + N_EDGES_C;
    const int*   batch    = (const int*)d_in[2];
    const float* Ws_all   = (const float*)d_in[3];
    const float* bs       = (const float*)d_in[4];
    const float* gammas   = (const float*)d_in[5];
    const float* betas    = (const float*)d_in[6];
    const float* run_mean = (const float*)d_in[7];
    const float* run_var  = (const float*)d_in[8];
    const float* W_out    = (const float*)d_in[9];
    const float* b_out    = (const float*)d_in[10];
    float* out = (float*)d_out;

    char* wp = (char*)d_ws;
    auto alloc = [&](size_t bytes) { char* p = wp; wp += (bytes + 255) & ~(size_t)255; return p; };
    __half*   h       = (__half*)alloc((size_t)N_NODES_C * HID * 2);
    _Float16* y       = (_Float16*)alloc((size_t)N_NODES_C * HID * 2);  // 25.6 MB
    int2*     ebuf    = (int2*)y;                                       // alias: dead before first k_gemm
    _Float16* xh      = (_Float16*)alloc((size_t)N_NODES_C * HID * 2);
    _Float16* WT      = (_Float16*)alloc((size_t)4 * HID * HID * 2);
    int*      csr_src = (int*)alloc((size_t)N_EDGES_C * 4);
    int*      offs    = (int*)alloc((size_t)(N_NODES_C + 1) * 4);
    float*    norm    = (float*)alloc((size_t)N_NODES_C * 4);
    int*      bcount  = (int*)alloc((NBUCK + 1) * 4);
    int*      bbase   = (int*)alloc((NBUCK + 1) * 4);
    int*      bcursor = (int*)alloc((NBUCK + 1) * 4);
    float*    psum    = (float*)alloc((size_t)N_GRAPHS_C * HID * 4);
    int*      pcount  = (int*)alloc((size_t)N_GRAPHS_C * 4);

    hipMemsetAsync(bcount, 0, (NBUCK + 1) * 4, stream);
    hipMemsetAsync(psum,   0, (size_t)N_GRAPHS_C * HID * 4, stream);
    hipMemsetAsync(pcount, 0, (size_t)N_GRAPHS_C * 4, stream);

    k_cast<<<(N_NODES_C * HID) / 2048, 256, 0, stream>>>(x, xh);   // 6250 blocks
    k_tw  <<<256, 256, 0, stream>>>(Ws_all, WT);

    const int PB = (N_EDGES_C + PART_TILE - 1) / PART_TILE;  // 391
    kb_hist<<<PB, 256, 0, stream>>>(dst, bcount);
    kb_scan<<<1, 512, 0, stream>>>(bcount, bbase, bcursor);
    kb_part<<<PB, 256, 0, stream>>>(src, dst, bcursor, ebuf);
    kb_fill<<<NBUCK, 256, 0, stream>>>(ebuf, bbase, csr_src, offs, norm);

    const int GB = (N_NODES_C + 127) / 128;   // 782
    const int AB = (N_NODES_C + 3) / 4;       // 25000
    for (int l = 0; l < 4; l++) {
        const _Float16* A = (l == 0) ? xh : (const _Float16*)h;
        k_gemm<<<GB, 256, 0, stream>>>(A, WT + (size_t)l * HID * HID, norm, y, N_NODES_C);
        k_agg<<<AB, 256, 0, stream>>>((const _Float16*)y, offs, csr_src, norm,
                                      bs + l * HID, run_mean + l * HID, gammas + l * HID,
                                      run_var + l * HID, betas + l * HID, (_Float16*)h);
    }
    k_pool <<<GB, 128, 0, stream>>>((const __half*)h, batch, psum, pcount);
    k_final<<<N_GRAPHS_C, 128, 0, stream>>>(psum, pcount, W_out, b_out, out);
}

// Round 3
// 532.424 us; speedup vs baseline: 1.0771x; 1.0771x over previous
//
#include <hip/hip_runtime.h>
#include <hip/hip_fp16.h>

#define N_NODES_C 100000
#define N_EDGES_C 1600000
#define N_GRAPHS_C 2000
#define HID 128
#define BN_EPS_C 1e-5f
#define NBUCK 391          // ceil(100000 / 256) buckets of 256 nodes
#define PART_TILE 4096     // edges per block in hist/partition kernels

typedef _Float16 half8 __attribute__((ext_vector_type(8)));
typedef float float4v __attribute__((ext_vector_type(4)));

// ---------------- CSR build: bucket partition ----------------

__global__ __launch_bounds__(256) void kb_hist(const int* __restrict__ dst, int* __restrict__ bcount) {
    __shared__ int hist[NBUCK];
    const int t = threadIdx.x;
    for (int b = t; b < NBUCK; b += 256) hist[b] = 0;
    __syncthreads();
    const int e0 = blockIdx.x * PART_TILE;
    #pragma unroll
    for (int k = 0; k < 16; k++) {
        int e = e0 + k * 256 + t;
        if (e < N_EDGES_C) atomicAdd(&hist[dst[e] >> 8], 1);
    }
    __syncthreads();
    for (int b = t; b < NBUCK; b += 256) {
        int c = hist[b];
        if (c) atomicAdd(&bcount[b], c);
    }
}

__global__ __launch_bounds__(512) void kb_scan(const int* __restrict__ bcount,
                                               int* __restrict__ bbase, int* __restrict__ bcursor) {
    __shared__ int s[512];
    const int t = threadIdx.x;
    int v = (t < NBUCK) ? bcount[t] : 0;
    s[t] = v;
    __syncthreads();
    for (int off = 1; off < 512; off <<= 1) {
        int u = (t >= off) ? s[t - off] : 0;
        __syncthreads();
        s[t] += u;
        __syncthreads();
    }
    if (t < NBUCK) { int e = s[t] - v; bbase[t] = e; bcursor[t] = e; }
    if (t == 0) bbase[NBUCK] = N_EDGES_C;
}

__global__ __launch_bounds__(256) void kb_part(const int* __restrict__ src, const int* __restrict__ dst,
                                               int* __restrict__ bcursor, int2* __restrict__ ebuf) {
    __shared__ int hist[NBUCK];
    __shared__ int startA[NBUCK];
    __shared__ int lcur[NBUCK];
    const int t = threadIdx.x;
    for (int b = t; b < NBUCK; b += 256) { hist[b] = 0; lcur[b] = 0; }
    __syncthreads();
    const int e0 = blockIdx.x * PART_TILE;
    #pragma unroll
    for (int k = 0; k < 16; k++) {
        int e = e0 + k * 256 + t;
        if (e < N_EDGES_C) atomicAdd(&hist[dst[e] >> 8], 1);
    }
    __syncthreads();
    for (int b = t; b < NBUCK; b += 256) {
        int c = hist[b];
        startA[b] = c ? atomicAdd(&bcursor[b], c) : 0;
    }
    __syncthreads();
    #pragma unroll
    for (int k = 0; k < 16; k++) {
        int e = e0 + k * 256 + t;
        if (e < N_EDGES_C) {
            int d = dst[e];
            int b = d >> 8;
            int pos = startA[b] + atomicAdd(&lcur[b], 1);
            ebuf[pos] = make_int2(src[e], d);
        }
    }
}

// One block per bucket: local count+scan of 256 nodes -> offs, norm, csr_src (all writes bucket-local).
__global__ __launch_bounds__(256) void kb_fill(const int2* __restrict__ ebuf, const int* __restrict__ bbase,
                                               int* __restrict__ csr_src, int* __restrict__ offs,
                                               float* __restrict__ norm) {
    __shared__ int s[256];
    __shared__ int excl[256];
    __shared__ int lcur[256];
    const int b = blockIdx.x, t = threadIdx.x;
    const int base = b << 8;
    const int e0 = bbase[b], e1 = bbase[b + 1];
    s[t] = 0; lcur[t] = 0;
    __syncthreads();
    for (int e = e0 + t; e < e1; e += 256)
        atomicAdd(&s[ebuf[e].y & 255], 1);
    __syncthreads();
    int own = s[t];
    for (int off = 1; off < 256; off <<= 1) {
        int v = (t >= off) ? s[t - off] : 0;
        __syncthreads();
        s[t] += v;
        __syncthreads();
    }
    excl[t] = s[t] - own;
    int node = base + t;
    if (node < N_NODES_C) {
        offs[node] = e0 + (s[t] - own);
        norm[node] = rsqrtf((float)own + 1.0f);
    }
    if (b == 0 && t == 0) offs[N_NODES_C] = N_EDGES_C;
    __syncthreads();
    for (int e = e0 + t; e < e1; e += 256) {
        int2 p = ebuf[e];
        int l = p.y & 255;
        int pos = e0 + excl[l] + atomicAdd(&lcur[l], 1);
        csr_src[pos] = p.x;
    }
}

// ---------------- precompute: x -> fp16, W -> fp16 transposed [n][k] ----------------

__global__ __launch_bounds__(256) void k_cast(const float* __restrict__ x, _Float16* __restrict__ xh) {
    long i = ((long)blockIdx.x * 256 + threadIdx.x) * 8;
    float4 a = *(const float4*)&x[i];
    float4 b = *(const float4*)&x[i + 4];
    _Float16 p[8] = {(_Float16)a.x, (_Float16)a.y, (_Float16)a.z, (_Float16)a.w,
                     (_Float16)b.x, (_Float16)b.y, (_Float16)b.z, (_Float16)b.w};
    *(half8*)&xh[i] = *(half8*)p;
}

__global__ __launch_bounds__(256) void k_tw(const float* __restrict__ Ws_all, _Float16* __restrict__ WT) {
    int idx = blockIdx.x * 256 + threadIdx.x;     // 4*128*128 = 65536
    int l = idx >> 14, r = idx & 16383, k = r >> 7, n = r & 127;
    WT[l * 16384 + n * HID + k] = (_Float16)Ws_all[idx];
}

// ---------------- MFMA GEMM: Y[r,:] = norm[r] * (A[r,:] @ W), fp16 in/out ----------------

__global__ __launch_bounds__(256) void k_gemm(const _Float16* __restrict__ Ah,
                                              const _Float16* __restrict__ WT,   // [128 n][128 k] fp16
                                              const float* __restrict__ norm,
                                              _Float16* __restrict__ Y, int nrows) {
    __shared__ _Float16 Wt[HID][136];   // [n][k], pitch 136 halves (272B: 2-way bank alias = free)
    const int tid = threadIdx.x;
    #pragma unroll
    for (int t = 0; t < 8; t++) {
        int off = tid * 8 + t * 2048;
        half8 v = *(const half8*)&WT[off];
        *(half8*)&Wt[off >> 7][off & 127] = v;
    }
    __syncthreads();

    const int wave = tid >> 6, lane = tid & 63, quad = lane >> 4, l16 = lane & 15;
    half8 Wf[2][4];
    #pragma unroll
    for (int c = 0; c < 2; c++)
        #pragma unroll
        for (int ks = 0; ks < 4; ks++)
            Wf[c][ks] = *(const half8*)&Wt[(wave * 2 + c) * 16 + l16][ks * 32 + quad * 8];

    const int nbase = blockIdx.x * 128;
    #pragma unroll
    for (int t = 0; t < 8; t++) {
        int node = nbase + t * 16 + l16;
        bool ok = node < nrows;
        half8 Af[4];
        const _Float16* arow = Ah + (long)node * HID;
        #pragma unroll
        for (int ks = 0; ks < 4; ks++)
            Af[ks] = ok ? *(const half8*)&arow[ks * 32 + quad * 8] : half8{};
        float4v a0 = {0.f, 0.f, 0.f, 0.f}, a1 = {0.f, 0.f, 0.f, 0.f};
        #pragma unroll
        for (int ks = 0; ks < 4; ks++) {
            a0 = __builtin_amdgcn_mfma_f32_16x16x32_f16(Wf[0][ks], Af[ks], a0, 0, 0, 0);
            a1 = __builtin_amdgcn_mfma_f32_16x16x32_f16(Wf[1][ks], Af[ks], a1, 0, 0, 0);
        }
        if (ok) {
            float nv = norm[node];
            _Float16 p0[4], p1[4];
            #pragma unroll
            for (int r = 0; r < 4; r++) {
                p0[r] = (_Float16)(a0[r] * nv);
                p1[r] = (_Float16)(a1[r] * nv);
            }
            *(ushort4*)&Y[(long)node * HID + (wave * 2 + 0) * 16 + quad * 4] = *(ushort4*)p0;
            *(ushort4*)&Y[(long)node * HID + (wave * 2 + 1) * 16 + quad * 4] = *(ushort4*)p1;
        }
    }
}

// ---------------- Aggregation + bias + BN(eval) + ReLU ----------------
// One wave per node, lane j handles channels (2j, 2j+1) via half2 -> wave-wide coalesced
// 256B row loads. Edge indices are WAVE-UNIFORM (readfirstlane'd wave id) -> scalar s_load
// index fetch + SGPR row base: near-zero VALU per gather. Edges processed in padded
// 16-edge chains: out-of-range slots are scalar-cselect'd to a zeroed DUMMY ROW (row
// N_NODES), so there is no serial tail and no vector masking.

__global__ __launch_bounds__(256) void k_agg(const __half* __restrict__ y, const int* __restrict__ offs,
                                             const int* __restrict__ csr_src, const float* __restrict__ norm,
                                             const float* __restrict__ bias, const float* __restrict__ mean,
                                             const float* __restrict__ gamma, const float* __restrict__ var,
                                             const float* __restrict__ beta, __half* __restrict__ h) {
    const int wave = __builtin_amdgcn_readfirstlane(threadIdx.x >> 6);
    const int lane = threadIdx.x & 63;
    const int i = blockIdx.x * 4 + wave;
    const int j = lane * 2;

    // self-loop term (y already scaled by norm[src] in k_gemm)
    float2 f = __half22float2(*(const __half2*)&y[(long)i * HID + j]);
    float acc0 = f.x, acc1 = f.y;

    const int e0 = offs[i], e1 = offs[i + 1];
    int e = e0;
    do {
        int id[16];
        #pragma unroll
        for (int u = 0; u < 16; u++) {
            int raw = csr_src[e + u];                    // scalar load (uniform addr)
            id[u] = (e + u < e1) ? raw : N_NODES_C;      // scalar cselect -> dummy zero row
        }
        #pragma unroll
        for (int u = 0; u < 16; u++) {
            float2 g = __half22float2(*(const __half2*)&y[(long)id[u] * HID + j]);
            acc0 += g.x; acc1 += g.y;
        }
        e += 16;
    } while (e < e1);

    const float ni = norm[i];
    float2 bi = *(const float2*)&bias[j];
    float2 me = *(const float2*)&mean[j];
    float2 ga = *(const float2*)&gamma[j];
    float2 va = *(const float2*)&var[j];
    float2 be = *(const float2*)&beta[j];
    float v0 = (acc0 * ni + bi.x - me.x) * (ga.x * rsqrtf(va.x + BN_EPS_C)) + be.x;
    float v1 = (acc1 * ni + bi.y - me.y) * (ga.y * rsqrtf(va.y + BN_EPS_C)) + be.y;
    *(__half2*)&h[(long)i * HID + j] = __floats2half2_rn(fmaxf(v0, 0.f), fmaxf(v1, 0.f));
}

// ---------------- Pooling (batch sorted -> run-length local accumulation) ----------------

__global__ __launch_bounds__(128) void k_pool(const __half* __restrict__ h, const int* __restrict__ batch,
                                              float* __restrict__ psum, int* __restrict__ pcount) {
    const int j = threadIdx.x;
    const int i0 = blockIdx.x * 128;
    const int iend = min(i0 + 128, N_NODES_C);
    if (i0 >= N_NODES_C) return;
    float acc = 0.f;
    int cur = batch[i0];
    int runStart = i0;
    for (int i = i0; i < iend; i++) {
        int g = batch[i];
        if (g != cur) {
            atomicAdd(&psum[(long)cur * HID + j], acc);
            if (j == 0) atomicAdd(&pcount[cur], i - runStart);
            acc = 0.f; cur = g; runStart = i;
        }
        acc += __half2float(h[(long)i * HID + j]);
    }
    atomicAdd(&psum[(long)cur * HID + j], acc);
    if (j == 0) atomicAdd(&pcount[cur], iend - runStart);
}

__global__ __launch_bounds__(128) void k_final(const float* __restrict__ psum, const int* __restrict__ pcount,
                                               const float* __restrict__ W_out, const float* __restrict__ b_out,
                                               float* __restrict__ out) {
    __shared__ float red[128][5];
    const int g = blockIdx.x, j = threadIdx.x;
    float cnt = fmaxf((float)pcount[g], 1.f);
    float p = psum[(long)g * HID + j] / cnt;
    #pragma unroll
    for (int o = 0; o < 5; o++) red[j][o] = p * W_out[j * 5 + o];
    __syncthreads();
    for (int off = 64; off >= 1; off >>= 1) {
        if (j < off) {
            #pragma unroll
            for (int o = 0; o < 5; o++) red[j][o] += red[j + off][o];
        }
        __syncthreads();
    }
    if (j < 5) out[g * 5 + j] = red[0][j] + b_out[j];
}

// ---------------- launch ----------------

extern "C" void kernel_launch(void* const* d_in, const int* in_sizes, int n_in,
                              void* d_out, int out_size, void* d_ws, size_t ws_size,
                              hipStream_t stream) {
    const float* x        = (const float*)d_in[0];
    const int*   eidx     = (const int*)d_in[1];
    const int*   src      = eidx;
    const int*   dst      = eidx + N_EDGES_C;
    const int*   batch    = (const int*)d_in[2];
    const float* Ws_all   = (const float*)d_in[3];
    const float* bs       = (const float*)d_in[4];
    const float* gammas   = (const float*)d_in[5];
    const float* betas    = (const float*)d_in[6];
    const float* run_mean = (const float*)d_in[7];
    const float* run_var  = (const float*)d_in[8];
    const float* W_out    = (const float*)d_in[9];
    const float* b_out    = (const float*)d_in[10];
    float* out = (float*)d_out;

    char* wp = (char*)d_ws;
    auto alloc = [&](size_t bytes) { char* p = wp; wp += (bytes + 255) & ~(size_t)255; return p; };
    __half*   h       = (__half*)alloc((size_t)N_NODES_C * HID * 2);
    _Float16* y       = (_Float16*)alloc((size_t)(N_NODES_C + 1) * HID * 2);  // +1 dummy zero row
    int2*     ebuf    = (int2*)y;                // alias: dead before first k_gemm; doesn't reach dummy row
    _Float16* xh      = (_Float16*)alloc((size_t)N_NODES_C * HID * 2);
    _Float16* WT      = (_Float16*)alloc((size_t)4 * HID * HID * 2);
    int*      csr_src = (int*)alloc((size_t)(N_EDGES_C + 16) * 4);  // +16 pad for 16-wide chain overread
    int*      offs    = (int*)alloc((size_t)(N_NODES_C + 1) * 4);
    float*    norm    = (float*)alloc((size_t)N_NODES_C * 4);
    int*      bcount  = (int*)alloc((NBUCK + 1) * 4);
    int*      bbase   = (int*)alloc((NBUCK + 1) * 4);
    int*      bcursor = (int*)alloc((NBUCK + 1) * 4);
    float*    psum    = (float*)alloc((size_t)N_GRAPHS_C * HID * 4);
    int*      pcount  = (int*)alloc((size_t)N_GRAPHS_C * 4);

    hipMemsetAsync(bcount, 0, (NBUCK + 1) * 4, stream);
    hipMemsetAsync(psum,   0, (size_t)N_GRAPHS_C * HID * 4, stream);
    hipMemsetAsync(pcount, 0, (size_t)N_GRAPHS_C * 4, stream);
    hipMemsetAsync(y + (size_t)N_NODES_C * HID, 0, HID * 2, stream);   // dummy row = 0
    hipMemsetAsync(csr_src + N_EDGES_C, 0, 16 * 4, stream);            // pad (values unused)

    k_cast<<<(N_NODES_C * HID) / 2048, 256, 0, stream>>>(x, xh);   // 6250 blocks
    k_tw  <<<256, 256, 0, stream>>>(Ws_all, WT);

    const int PB = (N_EDGES_C + PART_TILE - 1) / PART_TILE;  // 391
    kb_hist<<<PB, 256, 0, stream>>>(dst, bcount);
    kb_scan<<<1, 512, 0, stream>>>(bcount, bbase, bcursor);
    kb_part<<<PB, 256, 0, stream>>>(src, dst, bcursor, ebuf);
    kb_fill<<<NBUCK, 256, 0, stream>>>(ebuf, bbase, csr_src, offs, norm);

    const int GB = (N_NODES_C + 127) / 128;   // 782
    const int AB = (N_NODES_C + 3) / 4;       // 25000
    for (int l = 0; l < 4; l++) {
        const _Float16* A = (l == 0) ? xh : (const _Float16*)h;
        k_gemm<<<GB, 256, 0, stream>>>(A, WT + (size_t)l * HID * HID, norm, y, N_NODES_C);
        k_agg<<<AB, 256, 0, stream>>>((const __half*)y, offs, csr_src, norm,
                                      bs + l * HID, run_mean + l * HID, gammas + l * HID,
                                      run_var + l * HID, betas + l * HID, (__half*)h);
    }
    k_pool <<<GB, 128, 0, stream>>>((const __half*)h, batch, psum, pcount);
    k_final<<<N_GRAPHS_C, 128, 0, stream>>>(psum, pcount, W_out, b_out, out);
}